// Round 15
// baseline (349.610 us; speedup 1.0000x reference)
//
#include <hip/hip_runtime.h>
#include <hip/hip_fp16.h>
#include <math.h>

#define DIM 64
#define M_FINAL (128*89)   // 11392 final rows

static inline int cdiv(int a, int b) { return (a + b - 1) / b; }

typedef _Float16 v8h __attribute__((ext_vector_type(8)));
typedef _Float16 v4h __attribute__((ext_vector_type(4)));
typedef float v4f __attribute__((ext_vector_type(4)));

__device__ inline float rdlane(float v, int l) {
    return __int_as_float(__builtin_amdgcn_readlane(__float_as_int(v), l));
}
__device__ inline unsigned packpw(float p, unsigned src) {
    return ((unsigned)__half_as_ushort(__float2half(p)) << 16) | src;
}
__device__ inline float unpackpw(unsigned ep) {
    return __half2float(__ushort_as_half((unsigned short)(ep >> 16)));
}
__device__ inline __half2 u2h2(unsigned u) {
    union { unsigned u; __half2 h; } c; c.u = u; return c.h;
}

struct EdgeSets {
    const int* src[12];
    const int* dst[12];
    int ne[12];
};

struct L0Args {
    const float* x;
    __half* out[4];
    const int* rowptr[4];
    const int* colsrc[4];
    int ne[4];
    int nemax;
    double* dstats;
    const float* W;
    const float* as;
    const float* ad;
    const float* bias;
};

struct AggArgs {
    const __half* hp[4];      // projected rows (out-space, fp16)
    void* out[4];
    const int* rowptr[4];
    const int* colsrc[4];
    int ne[4];
    int nemax;
    const float* sS;          // [j][g][NPIN]
    const float* sD;
    const float* bias;
    double* dstats;
};

// ---------------- misc ----------------

__global__ void zero_kernel(float* __restrict__ p, int n) {
    int i = blockIdx.x * blockDim.x + threadIdx.x;
    if (i < n) p[i] = 0.f;
}

// ---------------- fused CSR build: one block per edge set ------------------
__global__ __launch_bounds__(768)
void csr_build_kernel(EdgeSets ES, int* __restrict__ rowptr_all,
                      int* __restrict__ colsrc_all) {
    __shared__ int cnt[768];
    __shared__ int cur[768];
    const int s = blockIdx.x;
    const int lay = s % 3;
    const int n = (lay == 0) ? 706 : (lay == 1) ? 353 : 177;
    const int ne = ES.ne[s];
    const int* __restrict__ src = ES.src[s];
    const int* __restrict__ dst = ES.dst[s];
    int* __restrict__ rowptr = rowptr_all + s * 768;
    int* __restrict__ colsrc = colsrc_all + s * 8192;
    const int t = threadIdx.x;

    cnt[t] = 0;
    __syncthreads();
    for (int k = t; k < ne; k += 768) atomicAdd(&cnt[dst[k]], 1);
    __syncthreads();
    int v = cnt[t];
    for (int off = 1; off < 768; off <<= 1) {
        int add = (t >= off) ? cnt[t - off] : 0;
        __syncthreads();
        cnt[t] += add;
        __syncthreads();
    }
    int excl = cnt[t] - v;
    if (t < n) { rowptr[t] = excl; cur[t] = excl; }
    if (t == n - 1) rowptr[n] = cnt[t];
    __syncthreads();
    for (int k = t; k < ne; k += 768) {
        int pos = atomicAdd(&cur[dst[k]], 1);
        colsrc[pos] = src[k];
    }
}

// ---------------- layer 0 mega kernel (in_dim=3, thread-par agg) -----------
// grid = split(2) x view(4) x graph(128) = 1024 blocks of 512 threads.
__global__ __launch_bounds__(512, 8)
void layer0_kernel(L0Args A) {
    constexpr int NPIN = 706, NPOUT = 353, HALF = 177;

    extern __shared__ char smem[];
    float* sredF = (float*)smem;                       // [2][8][64] = 4096 B
    float* fp = (float*)(smem + 4096);
    float* sSrc = fp; fp += NPIN;
    float* sDst = fp; fp += NPIN;
    float* hL4  = fp; fp += NPIN * 4;
    float* agg4 = fp; fp += 356 * 4;
    float* waL0 = fp; fp += 8;
    unsigned short* rp16 = (unsigned short*)fp;        // 708

    const int split = blockIdx.x >> 9;
    const int jg = blockIdx.x & 511;
    const int j = jg >> 7;
    const int g = jg & 127;
    const int tid = threadIdx.x;
    const int wave = tid >> 6;
    const int lane = tid & 63;

    const int n0c = split * HALF;
    const int n1c = min(NPOUT, n0c + HALF);
    const int ch0 = 2 * n0c;
    const int ch1 = 2 * n1c;          // NPIN even -> always valid children

    const int* __restrict__ rowptr = A.rowptr[j];
    const int* __restrict__ colsrc = A.colsrc[j];
    const float* __restrict__ W = A.W;

    for (int k = tid; k <= NPIN; k += 512) rp16[k] = (unsigned short)rowptr[k];
    if (tid < 6) {                    // wa_{src,dst}[f] = sum_d W[f][d]*a[d]
        int f = (tid < 3) ? tid : tid - 3;
        const float* av = (tid < 3) ? A.as : A.ad;
        float acc = 0.f;
        for (int d = 0; d < 64; ++d) acc += W[f * 64 + d] * av[d];
        waL0[tid] = acc;
    }
    __syncthreads();

    // h staging + s-dots
    {
        const float* hb = A.x + (size_t)g * (NPIN * 3);
        for (int r = tid; r < NPIN; r += 512) {
            float h0 = hb[r * 3], h1 = hb[r * 3 + 1], h2 = hb[r * 3 + 2];
            hL4[r * 4] = h0; hL4[r * 4 + 1] = h1; hL4[r * 4 + 2] = h2; hL4[r * 4 + 3] = 0.f;
            sSrc[r] = h0 * waL0[0] + h1 * waL0[1] + h2 * waL0[2];
            sDst[r] = h0 * waL0[3] + h1 * waL0[4] + h2 * waL0[5];
        }
    }
    __syncthreads();

    // thread-par softmax + aggregation: one child per thread
    const int child = ch0 + tid;
    if (child < ch1) {
        int s0 = rp16[child], e0 = rp16[child + 1];
        float sd = sDst[child];
        float m = -1e30f;
        for (int k = s0; k < e0; ++k) {
            float v = sSrc[colsrc[k]] + sd;
            v = (v >= 0.f) ? v : 0.2f * v;
            m = fmaxf(m, v);
        }
        float z = 0.f, a0 = 0.f, a1 = 0.f, a2 = 0.f;
        for (int k = s0; k < e0; ++k) {
            int sl = colsrc[k];
            float v = sSrc[sl] + sd;
            v = (v >= 0.f) ? v : 0.2f * v;
            float p = __expf(v - m);
            z += p;
            a0 += p * hL4[sl * 4];
            a1 += p * hL4[sl * 4 + 1];
            a2 += p * hL4[sl * 4 + 2];
        }
        float iz = 1.f / z;
        agg4[tid * 4]     = a0 * iz;
        agg4[tid * 4 + 1] = a1 * iz;
        agg4[tid * 4 + 2] = a2 * iz;
        agg4[tid * 4 + 3] = 0.f;
    }
    __syncthreads();

    // wave-par matvec + relu + pool + store + BN stats
    const float w0 = W[lane], w1 = W[64 + lane], w2 = W[128 + lane];
    const float b_l = A.bias[lane];
    __half* outj = A.out[j];
    const float4* agg4v = (const float4*)agg4;
    float bs = 0.f, bs2 = 0.f;

    for (int c = n0c + wave; c < n1c; c += 8) {
        int lc = 2 * (c - n0c);
        float4 va = agg4v[lc];
        float4 vb = agg4v[lc + 1];
        float oa = va.x * w0 + va.y * w1 + va.z * w2 + b_l;
        float ob = vb.x * w0 + vb.y * w1 + vb.z * w2 + b_l;
        float vmax = fmaxf(fmaxf(oa, ob), 0.f);
        outj[((size_t)g * NPOUT + c) * 64 + lane] = __float2half(vmax);
        bs += vmax;
        bs2 += vmax * vmax;
    }
    sredF[wave * 64 + lane] = bs;
    sredF[512 + wave * 64 + lane] = bs2;
    __syncthreads();
    if (wave == 0) {
        float t1 = 0.f, t2 = 0.f;
        #pragma unroll
        for (int w = 0; w < 8; ++w) {
            t1 += sredF[w * 64 + lane];
            t2 += sredF[512 + w * 64 + lane];
        }
        atomicAdd(A.dstats + j * 128 + lane, (double)t1);
        atomicAdd(A.dstats + j * 128 + 64 + lane, (double)t2);
    }
}

// BN finalize; optionally fold stats into next layer's weight:
// Wp[f][d] = rs[f]*Wn[f][d]; csh[d] = sum_f mu[f]*rs[f]*Wn[f][d]
__global__ void bn_finalize_kernel(const double* __restrict__ dstats,
                                   float* __restrict__ musig, int n_rows,
                                   const float* __restrict__ Wn,
                                   float* __restrict__ Wp, float* __restrict__ csh) {
    __shared__ float mur[128];
    int jv = blockIdx.x;           // view
    int d = threadIdx.x;           // 64
    double mu = dstats[jv * 128 + d] / n_rows;
    double var = dstats[jv * 128 + 64 + d] / n_rows - mu * mu;
    float rs = rsqrtf((float)var + 1e-5f);
    musig[jv * 128 + d] = (float)mu;
    musig[jv * 128 + 64 + d] = rs;
    if (Wn != nullptr) {
        mur[d] = (float)mu; mur[64 + d] = rs;
        __syncthreads();
        float c = 0.f;
        for (int f = 0; f < 64; ++f) {
            float wp = mur[64 + f] * Wn[f * 64 + d];
            Wp[jv * 4096 + f * 64 + d] = wp;
            c += mur[f] * wp;
        }
        csh[jv * 64 + d] = c;
    }
}

// ---------------- projection via MFMA: HP = h @ W' - c, fp16 in-place ------
__global__ __launch_bounds__(256, 4)
void proj_kernel(__half* __restrict__ buf, const float* __restrict__ Wp_all,
                 const float* __restrict__ csh_all,
                 const float* __restrict__ a_s, const float* __restrict__ a_d,
                 float* __restrict__ sS, float* __restrict__ sD, int npin) {
    __shared__ _Float16 Wt[64 * 64];   // Wt[d][f] = W'[f][d], fp16 (8 KB)
    const int j = blockIdx.y;
    const int tid = threadIdx.x;
    const int lane = tid & 63, wave = tid >> 6;
    const int lc = lane & 15, quad = lane >> 4;
    const int R = 128 * npin;          // multiple of 16
    __half* h = buf + (size_t)j * R * 64;
    const float* Wp = Wp_all + j * 4096;

    for (int k = tid; k < 4096; k += 256) {
        int f = k >> 6, d = k & 63;
        Wt[d * 64 + f] = (_Float16)Wp[k];
    }
    __syncthreads();

    v8h bfrag[4][2];
    #pragma unroll
    for (int t = 0; t < 4; ++t)
        #pragma unroll
        for (int s = 0; s < 2; ++s)
            bfrag[t][s] = *(const v8h*)&Wt[(t * 16 + lc) * 64 + s * 32 + quad * 8];

    float cshv[4], asv[4], adv[4];
    #pragma unroll
    for (int t = 0; t < 4; ++t) {
        cshv[t] = csh_all[j * 64 + t * 16 + lc];
        asv[t] = a_s[t * 16 + lc];
        adv[t] = a_d[t * 16 + lc];
    }

    const int ntiles = R >> 4;
    for (int tile = blockIdx.x * 4 + wave; tile < ntiles; tile += gridDim.x * 4) {
        const int rowbase = tile * 16;
        const __half* arow = h + ((size_t)(rowbase + lc)) * 64 + quad * 8;
        v8h a0 = *(const v8h*)arow;            // k-step 0 (k=0..31)
        v8h a1 = *(const v8h*)(arow + 32);     // k-step 1 (k=32..63)
        v4f acc[4];
        #pragma unroll
        for (int t = 0; t < 4; ++t) {
            acc[t] = (v4f){0.f, 0.f, 0.f, 0.f};
            acc[t] = __builtin_amdgcn_mfma_f32_16x16x32_f16(a0, bfrag[t][0], acc[t], 0, 0, 0);
            acc[t] = __builtin_amdgcn_mfma_f32_16x16x32_f16(a1, bfrag[t][1], acc[t], 0, 0, 0);
        }
        float pS[4] = {0.f, 0.f, 0.f, 0.f};
        float pD[4] = {0.f, 0.f, 0.f, 0.f};
        #pragma unroll
        for (int t = 0; t < 4; ++t) {
            #pragma unroll
            for (int r = 0; r < 4; ++r) {
                float o = acc[t][r] - cshv[t];
                h[((size_t)(rowbase + quad * 4 + r)) * 64 + t * 16 + lc] = __float2half(o);
                pS[r] += o * asv[t];
                pD[r] += o * adv[t];
            }
        }
        #pragma unroll
        for (int m = 1; m < 16; m <<= 1) {
            #pragma unroll
            for (int r = 0; r < 4; ++r) {
                pS[r] += __shfl_xor(pS[r], m, 64);
                pD[r] += __shfl_xor(pD[r], m, 64);
            }
        }
        if (lc == 0) {
            #pragma unroll
            for (int r = 0; r < 4; ++r) {
                sS[j * R + rowbase + quad * 4 + r] = pS[r];
                sD[j * R + rowbase + quad * 4 + r] = pD[r];
            }
        }
    }
}

// ---------------- aggregation (L>0): quad-row gather, packed fp16 FMA ------
// grid = split(4) x view(4) x graph(128) = 2048 blocks of 512 threads.
// Each block stages only its own contiguous edge slice; 16-edge unroll puts
// 4 independent loads in flight.
template<int NPIN, typename OutT>
__global__ __launch_bounds__(512, 8)
void agg_kernel(AggArgs A) {
    constexpr int NPOUT = (NPIN + 1) / 2;
    constexpr int QTR = (NPOUT + 3) / 4;

    extern __shared__ char smem[];
    float* sredF = (float*)smem;                       // 4096 B
    float* fp = (float*)(smem + 4096);
    float* sSrc = fp; fp += NPIN;
    float* sDst = fp; fp += NPIN;
    unsigned* ep32 = (unsigned*)fp;
    unsigned short* rp16 = (unsigned short*)(ep32 + A.nemax);

    const int split = blockIdx.x >> 9;                 // 0..3
    const int jg = blockIdx.x & 511;
    const int j = jg >> 7;
    const int g = jg & 127;
    const int tid = threadIdx.x;
    const int wave = tid >> 6;
    const int lane = tid & 63;
    const int qg = lane >> 4;          // edge-group 0..3
    const int lc = lane & 15;          // dim-group: dims 4*lc .. 4*lc+3

    const int n0c = split * QTR;
    const int n1c = min(NPOUT, n0c + QTR);
    const int ch0 = 2 * n0c;
    const int ch1 = min(NPIN, 2 * n1c);

    const int* __restrict__ rowptr = A.rowptr[j];
    const int* __restrict__ colsrc = A.colsrc[j];
    const int sbase = (j * 128 + g) * NPIN;
    const __half* __restrict__ hpb = A.hp[j] + (size_t)g * NPIN * 64 + 4 * lc;

    const int es0 = rowptr[ch0];
    const int es1 = rowptr[ch1];

    for (int k = tid; k <= NPIN; k += 512) rp16[k] = (unsigned short)rowptr[k];
    for (int k = es0 + tid; k < es1; k += 512) ep32[k - es0] = (unsigned)colsrc[k];
    for (int r = tid; r < NPIN; r += 512) {
        sSrc[r] = A.sS[sbase + r];
        sDst[r] = A.sD[sbase + r];
    }
    __syncthreads();

    // per-node online softmax -> packed fp16 weights (own child range)
    for (int r = ch0 + tid; r < ch1; r += 512) {
        int s0 = rp16[r] - es0, e0 = rp16[r + 1] - es0;
        float sd = sDst[r];
        float m = -1e30f, z = 0.f;
        for (int k = s0; k < e0; ++k) {
            float v = sSrc[ep32[k] & 0xFFFFu] + sd;
            v = (v >= 0.f) ? v : 0.2f * v;
            if (v > m) { z = z * __expf(m - v) + 1.f; m = v; }
            else z += __expf(v - m);
        }
        float invz = 1.f / z;
        for (int k = s0; k < e0; ++k) {
            unsigned sl = ep32[k] & 0xFFFFu;
            float v = sSrc[sl] + sd;
            v = (v >= 0.f) ? v : 0.2f * v;
            ep32[k] = packpw(__expf(v - m) * invz, sl);
        }
    }
    __syncthreads();

    const float4 b4 = *(const float4*)(A.bias + 4 * lc);
    OutT* outj = (OutT*)A.out[j];
    float bs[4] = {0.f, 0.f, 0.f, 0.f};
    float bs2[4] = {0.f, 0.f, 0.f, 0.f};

    for (int c = n0c + wave; c < n1c; c += 8) {
        float vch[2][4];
        #pragma unroll
        for (int ch = 0; ch < 2; ++ch) {
            __half2 aA0 = u2h2(0), aA1 = u2h2(0);   // chain A
            __half2 aB0 = u2h2(0), aB1 = u2h2(0);   // chain B
            int child = 2 * c + ch;
            if (child < NPIN) {
                int s0 = rp16[child] - es0, e0 = rp16[child + 1] - es0;
                int k = s0;
                for (; k + 16 <= e0; k += 16) {     // 4 loads in flight
                    unsigned ea = ep32[k + qg];
                    unsigned eb = ep32[k + 4 + qg];
                    unsigned ec = ep32[k + 8 + qg];
                    unsigned ed = ep32[k + 12 + qg];
                    uint2 u0 = *(const uint2*)(hpb + (size_t)(ea & 0xFFFFu) * 64);
                    uint2 u1 = *(const uint2*)(hpb + (size_t)(eb & 0xFFFFu) * 64);
                    uint2 u2 = *(const uint2*)(hpb + (size_t)(ec & 0xFFFFu) * 64);
                    uint2 u3 = *(const uint2*)(hpb + (size_t)(ed & 0xFFFFu) * 64);
                    __half2 p0 = u2h2((ea & 0xFFFF0000u) | (ea >> 16));
                    __half2 p1 = u2h2((eb & 0xFFFF0000u) | (eb >> 16));
                    __half2 p2 = u2h2((ec & 0xFFFF0000u) | (ec >> 16));
                    __half2 p3 = u2h2((ed & 0xFFFF0000u) | (ed >> 16));
                    aA0 = __hfma2(u2h2(u0.x), p0, aA0);
                    aA1 = __hfma2(u2h2(u0.y), p0, aA1);
                    aB0 = __hfma2(u2h2(u1.x), p1, aB0);
                    aB1 = __hfma2(u2h2(u1.y), p1, aB1);
                    aA0 = __hfma2(u2h2(u2.x), p2, aA0);
                    aA1 = __hfma2(u2h2(u2.y), p2, aA1);
                    aB0 = __hfma2(u2h2(u3.x), p3, aB0);
                    aB1 = __hfma2(u2h2(u3.y), p3, aB1);
                }
                for (; k + 8 <= e0; k += 8) {
                    unsigned e0p = ep32[k + qg];
                    unsigned e1p = ep32[k + 4 + qg];
                    uint2 u0 = *(const uint2*)(hpb + (size_t)(e0p & 0xFFFFu) * 64);
                    uint2 u1 = *(const uint2*)(hpb + (size_t)(e1p & 0xFFFFu) * 64);
                    __half2 p0 = u2h2((e0p & 0xFFFF0000u) | (e0p >> 16));
                    __half2 p1 = u2h2((e1p & 0xFFFF0000u) | (e1p >> 16));
                    aA0 = __hfma2(u2h2(u0.x), p0, aA0);
                    aA1 = __hfma2(u2h2(u0.y), p0, aA1);
                    aB0 = __hfma2(u2h2(u1.x), p1, aB0);
                    aB1 = __hfma2(u2h2(u1.y), p1, aB1);
                }
                for (; k < e0; k += 4) {
                    int idx = k + qg;
                    unsigned ep = ep32[(idx < e0) ? idx : (e0 - 1)];
                    uint2 u0 = *(const uint2*)(hpb + (size_t)(ep & 0xFFFFu) * 64);
                    unsigned pb = (idx < e0) ? ((ep & 0xFFFF0000u) | (ep >> 16)) : 0u;
                    __half2 p0 = u2h2(pb);
                    aA0 = __hfma2(u2h2(u0.x), p0, aA0);
                    aA1 = __hfma2(u2h2(u0.y), p0, aA1);
                }
            }
            float2 f0 = __half22float2(aA0), f1 = __half22float2(aA1);
            float2 g0 = __half22float2(aB0), g1 = __half22float2(aB1);
            vch[ch][0] = f0.x + g0.x;
            vch[ch][1] = f0.y + g0.y;
            vch[ch][2] = f1.x + g1.x;
            vch[ch][3] = f1.y + g1.y;
        }
        // reduce over the 4 edge-groups
        #pragma unroll
        for (int m = 16; m < 64; m <<= 1) {
            #pragma unroll
            for (int r = 0; r < 4; ++r) {
                vch[0][r] += __shfl_xor(vch[0][r], m, 64);
                vch[1][r] += __shfl_xor(vch[1][r], m, 64);
            }
        }
        float vm[4];
        #pragma unroll
        for (int r = 0; r < 4; ++r) {
            float oa = vch[0][r] + ((const float*)&b4)[r];
            float ob = vch[1][r] + ((const float*)&b4)[r];
            vm[r] = fmaxf(fmaxf(oa, ob), 0.f);
            bs[r] += vm[r];
            bs2[r] += vm[r] * vm[r];
        }
        if (qg == 0) {
            if constexpr (sizeof(OutT) == 2) {
                v4h hv;
                #pragma unroll
                for (int r = 0; r < 4; ++r) hv[r] = (_Float16)vm[r];
                *(v4h*)((__half*)outj + ((size_t)g * NPOUT + c) * 64 + 4 * lc) = hv;
            } else {
                float4 fv = {vm[0], vm[1], vm[2], vm[3]};
                *(float4*)((float*)outj + ((size_t)g * NPOUT + c) * 64 + 4 * lc) = fv;
            }
        }
    }
    // stats: post-reduce values identical across qg; qg==0 lanes cover all 64 dims
    if (qg == 0) {
        #pragma unroll
        for (int r = 0; r < 4; ++r) {
            sredF[wave * 64 + 4 * lc + r] = bs[r];
            sredF[512 + wave * 64 + 4 * lc + r] = bs2[r];
        }
    }
    __syncthreads();
    if (wave == 0) {
        float t1 = 0.f, t2 = 0.f;
        #pragma unroll
        for (int w = 0; w < 8; ++w) {
            t1 += sredF[w * 64 + lane];
            t2 += sredF[512 + w * 64 + lane];
        }
        atomicAdd(A.dstats + j * 128 + lane, (double)t1);
        atomicAdd(A.dstats + j * 128 + 64 + lane, (double)t2);
    }
}

// ---------------- fused head reduce: Bm dots -> S (BmT Bm) + column means --
__global__ __launch_bounds__(256)
void head_reduce_kernel(const float* __restrict__ ALL, const float* __restrict__ musig,
                        const float* __restrict__ w_attn,
                        float* __restrict__ S, float* __restrict__ cm) {
    __shared__ float S_loc[16];
    __shared__ float cm_loc[256];
    const int t = threadIdx.x, wave = t >> 6, lane = t & 63;
    if (t < 16) S_loc[t] = 0.f;
    cm_loc[t] = 0.f;
    __syncthreads();
    const float wa = w_attn[lane];
    float cacc[4] = {0.f, 0.f, 0.f, 0.f};
    for (int m = blockIdx.x * 4 + wave; m < M_FINAL; m += gridDim.x * 4) {
        float b4[4];
        float csum = 0.f;
        #pragma unroll
        for (int v = 0; v < 4; ++v) {
            float val = (ALL[((size_t)v * M_FINAL + m) * 64 + lane] - musig[v * 128 + lane])
                        * musig[v * 128 + 64 + lane];
            csum += val;
            float p = val * wa;
            for (int off = 32; off > 0; off >>= 1) p += __shfl_down(p, off, 64);
            b4[v] = __shfl(p, 0, 64);
        }
        cacc[m & 3] += csum;
        if (lane < 16) atomicAdd(&S_loc[lane], b4[lane >> 2] * b4[lane & 3]);
    }
    #pragma unroll
    for (int q = 0; q < 4; ++q) atomicAdd(&cm_loc[q * 64 + lane], cacc[q]);
    __syncthreads();
    if (t < 16) atomicAdd(&S[t], S_loc[t]);
    atomicAdd(&cm[t], cm_loc[t]);
}

// wave-parallel: 64 lanes split the 256-column mean-dot; lane 0 does the
// tiny 4x4 softmax tail.
__global__ void fuse_small_kernel(const float* __restrict__ S, const float* __restrict__ cm,
                                  const float* __restrict__ w_lin0, const float* __restrict__ b_lin0,
                                  float* __restrict__ cvec) {
    const int lane = threadIdx.x;      // 64
    float pa0 = 0.f, pa1 = 0.f, pa2 = 0.f, pa3 = 0.f;
    #pragma unroll
    for (int q = 0; q < 4; ++q) {
        int c = q * 64 + lane;
        float cmv = cm[c] / (float)M_FINAL;
        pa0 += cmv * w_lin0[c * 4 + 0];
        pa1 += cmv * w_lin0[c * 4 + 1];
        pa2 += cmv * w_lin0[c * 4 + 2];
        pa3 += cmv * w_lin0[c * 4 + 3];
    }
    for (int off = 32; off > 0; off >>= 1) {
        pa0 += __shfl_down(pa0, off, 64);
        pa1 += __shfl_down(pa1, off, 64);
        pa2 += __shfl_down(pa2, off, 64);
        pa3 += __shfl_down(pa3, off, 64);
    }
    if (lane != 0) return;
    float e4[4] = {pa0 + b_lin0[0], pa1 + b_lin0[1], pa2 + b_lin0[2], pa3 + b_lin0[3]};
    float cn[4];
    for (int v = 0; v < 4; ++v) cn[v] = sqrtf(S[v * 4 + v]);
    float A[16];
    for (int u = 0; u < 4; ++u) {
        float row[4]; float mx = -1e30f;
        for (int v = 0; v < 4; ++v) {
            float g = S[u * 4 + v] / (cn[u] * cn[v]);
            g = (g >= 0.f) ? g : 0.1f * g;       // leaky_relu 0.1
            row[v] = g; mx = fmaxf(mx, g);
        }
        float sum = 0.f;
        for (int v = 0; v < 4; ++v) { row[v] = expf(row[v] - mx); sum += row[v]; }
        for (int v = 0; v < 4; ++v) A[u * 4 + v] = row[v] / sum;
    }
    float mx = fmaxf(fmaxf(e4[0], e4[1]), fmaxf(e4[2], e4[3]));
    float sum = 0.f, w[4];
    for (int v = 0; v < 4; ++v) { w[v] = expf(e4[v] - mx); sum += w[v]; }
    for (int v = 0; v < 4; ++v) w[v] /= sum;
    for (int k = 0; k < 4; ++k) {
        float c = 0.f;
        for (int v = 0; v < 4; ++v) c += A[k * 4 + v] * w[v];
        cvec[k] = c;
    }
}

// ---------------- fused head output: combine + 3 matvecs (selu,selu,none) --
__global__ __launch_bounds__(256)
void head_out_kernel(const float* __restrict__ ALL, const float* __restrict__ musig,
                     const float* __restrict__ cvec,
                     const float* __restrict__ W0, const float* __restrict__ W1,
                     const float* __restrict__ W2, float* __restrict__ outp) {
    __shared__ float Wl[3][64 * 64];   // 48 KB
    const int t = threadIdx.x, wave = t >> 6, lane = t & 63;
    for (int k = t; k < 4096; k += 256) {
        Wl[0][k] = W0[k]; Wl[1][k] = W1[k]; Wl[2][k] = W2[k];
    }
    __syncthreads();
    const float c0 = cvec[0], c1 = cvec[1], c2 = cvec[2], c3 = cvec[3];
    const float scale = 1.0507009873554805f;
    const float alpha = 1.6732632423543772f;
    for (int m = blockIdx.x * 4 + wave; m < M_FINAL; m += gridDim.x * 4) {
        float r =
            c0 * ((ALL[((size_t)0 * M_FINAL + m) * 64 + lane] - musig[0 * 128 + lane]) * musig[0 * 128 + 64 + lane]) +
            c1 * ((ALL[((size_t)1 * M_FINAL + m) * 64 + lane] - musig[1 * 128 + lane]) * musig[1 * 128 + 64 + lane]) +
            c2 * ((ALL[((size_t)2 * M_FINAL + m) * 64 + lane] - musig[2 * 128 + lane]) * musig[2 * 128 + 64 + lane]) +
            c3 * ((ALL[((size_t)3 * M_FINAL + m) * 64 + lane] - musig[3 * 128 + lane]) * musig[3 * 128 + 64 + lane]);
        #pragma unroll
        for (int s = 0; s < 3; ++s) {
            float o0 = 0.f, o1 = 0.f, o2 = 0.f, o3 = 0.f;
            #pragma unroll
            for (int f = 0; f < 64; f += 4) {
                o0 += rdlane(r, f)     * Wl[s][f * 64 + lane];
                o1 += rdlane(r, f + 1) * Wl[s][(f + 1) * 64 + lane];
                o2 += rdlane(r, f + 2) * Wl[s][(f + 2) * 64 + lane];
                o3 += rdlane(r, f + 3) * Wl[s][(f + 3) * 64 + lane];
            }
            float o = (o0 + o1) + (o2 + o3);
            if (s < 2) o = (o > 0.f) ? scale * o : scale * alpha * expm1f(o);
            r = o;
        }
        outp[(size_t)m * 64 + lane] = r;
    }
}

extern "C" void kernel_launch(void* const* d_in, const int* in_sizes, int n_in,
                              void* d_out, int out_size, void* d_ws, size_t ws_size,
                              hipStream_t stream) {
    const float* x = (const float*)d_in[15];

    float* ws = (float*)d_ws;
    double* dstats_all = (double*)ws;                 // 1536 doubles -> [0, 3072)
    float*  cm         = ws + 3072;                   // 256
    float*  S          = ws + 3328;                   // 16
    float*  cvec       = ws + 3344;                   // 4
    float*  musig_all  = ws + 3584;                   // 3*512 -> [3584, 5120)
    float*  Wp_all     = ws + 5120;                   // 2*4*4096 -> [5120, 37888)
    float*  csh_all    = ws + 37888;                  // 2*4*64 -> [37888, 38400)
    int*    rowptr_all = (int*)(ws + 38400);          // 12*768 -> [38400, 47616)
    int*    colsrc_all = (int*)(ws + 47616);          // 12*8192 -> [47616, 145920)
    float*  sS1        = ws + 145920;                 // 180736
    float*  sD1        = sS1 + 180736;
    float*  sS2        = sD1 + 180736;                // 90624
    float*  sD2        = sS2 + 90624;
    __half* A16        = (__half*)(sD2 + 90624);      // 11,567,104 halves (5,783,552 slots)
    __half* B16        = (__half*)((float*)A16 + 5783552);  // 5,799,936 halves (2,899,968 slots)
    float*  ALLb       = (float*)B16 + 2899968;       // 2,916,352 floats
    const size_t as0h = (size_t)128 * 353 * 64;       // halves per view (layer0/1)
    const size_t as1h = (size_t)128 * 177 * 64;

    // edge sets (graph-0 structure shared by all 128 graphs)
    EdgeSets ES;
    int nemax[3] = {0, 0, 0};
    for (int s = 0; s < 12; ++s) {
        const int* e = (const int*)d_in[s];
        int E = in_sizes[s] / 2;
        ES.src[s] = e;
        ES.dst[s] = e + E;
        ES.ne[s] = E / 128;
        int lay = s % 3;
        if (ES.ne[s] > nemax[lay]) nemax[lay] = ES.ne[s];
    }

    // dynamic LDS sizes (mirror in-kernel layouts)
    int SM0 = 4096 + (706 * 6 + 356 * 4 + 8) * 4 + 708 * 2;
    SM0 = (SM0 + 15) & ~15;
    int SMa1 = 4096 + (2 * 353) * 4 + nemax[1] * 4 + 355 * 2;
    SMa1 = (SMa1 + 15) & ~15;
    int SMa2 = 4096 + (2 * 177) * 4 + nemax[2] * 4 + 179 * 2;
    SMa2 = (SMa2 + 15) & ~15;
    (void)hipFuncSetAttribute(reinterpret_cast<const void*>(&layer0_kernel),
                              hipFuncAttributeMaxDynamicSharedMemorySize, SM0);
    (void)hipFuncSetAttribute(reinterpret_cast<const void*>(&agg_kernel<353, __half>),
                              hipFuncAttributeMaxDynamicSharedMemorySize, SMa1);
    (void)hipFuncSetAttribute(reinterpret_cast<const void*>(&agg_kernel<177, float>),
                              hipFuncAttributeMaxDynamicSharedMemorySize, SMa2);

    zero_kernel<<<cdiv(3584, 256), 256, 0, stream>>>(ws, 3584);
    csr_build_kernel<<<12, 768, 0, stream>>>(ES, rowptr_all, colsrc_all);

    // ---- layer 0 -> fp16 raw0 in A16 ----
    {
        L0Args A;
        A.x = x;
        for (int j = 0; j < 4; ++j) {
            int s = j * 3;
            A.rowptr[j] = rowptr_all + s * 768;
            A.colsrc[j] = colsrc_all + s * 8192;
            A.ne[j] = ES.ne[s];
            A.out[j] = A16 + j * as0h;
        }
        A.nemax = nemax[0];
        A.dstats = dstats_all;
        A.W = (const float*)d_in[16];
        A.as = (const float*)d_in[17];
        A.ad = (const float*)d_in[18];
        A.bias = (const float*)d_in[19];
        layer0_kernel<<<1024, 512, SM0, stream>>>(A);
    }
    bn_finalize_kernel<<<4, 64, 0, stream>>>(dstats_all, musig_all, 128 * 353,
                                             (const float*)d_in[20], Wp_all, csh_all);

    // ---- layer 1: in-place fp16 MFMA proj on A16, then aggregate -> B16 ---
    proj_kernel<<<dim3(256, 4), 256, 0, stream>>>(A16, Wp_all, csh_all,
                                                  (const float*)d_in[21], (const float*)d_in[22],
                                                  sS1, sD1, 353);
    {
        AggArgs A;
        for (int j = 0; j < 4; ++j) {
            int s = j * 3 + 1;
            A.rowptr[j] = rowptr_all + s * 768;
            A.colsrc[j] = colsrc_all + s * 8192;
            A.ne[j] = ES.ne[s];
            A.hp[j] = A16 + j * as0h;
            A.out[j] = B16 + j * as1h;
        }
        A.nemax = nemax[1];
        A.sS = sS1; A.sD = sD1;
        A.bias = (const float*)d_in[23];
        A.dstats = dstats_all + 512;
        agg_kernel<353, __half><<<2048, 512, SMa1, stream>>>(A);
    }
    bn_finalize_kernel<<<4, 64, 0, stream>>>(dstats_all + 512, musig_all + 512, 128 * 177,
                                             (const float*)d_in[24], Wp_all + 16384, csh_all + 256);

    // ---- layer 2: in-place fp16 MFMA proj on B16, then aggregate -> ALLb --
    proj_kernel<<<dim3(256, 4), 256, 0, stream>>>(B16, Wp_all + 16384, csh_all + 256,
                                                  (const float*)d_in[25], (const float*)d_in[26],
                                                  sS2, sD2, 177);
    {
        AggArgs A;
        for (int j = 0; j < 4; ++j) {
            int s = j * 3 + 2;
            A.rowptr[j] = rowptr_all + s * 768;
            A.colsrc[j] = colsrc_all + s * 8192;
            A.ne[j] = ES.ne[s];
            A.hp[j] = B16 + j * as1h;
            A.out[j] = ALLb + (size_t)j * M_FINAL * 64;
        }
        A.nemax = nemax[2];
        A.sS = sS2; A.sD = sD2;
        A.bias = (const float*)d_in[27];
        A.dstats = dstats_all + 1024;
        agg_kernel<177, float><<<2048, 512, SMa2, stream>>>(A);
    }
    bn_finalize_kernel<<<4, 64, 0, stream>>>(dstats_all + 1024, musig_all + 1024, 128 * 89,
                                             nullptr, nullptr, nullptr);

    // ---- fusion head ----
    const float* musig2 = musig_all + 1024;
    head_reduce_kernel<<<256, 256, 0, stream>>>(ALLb, musig2, (const float*)d_in[28], S, cm);
    fuse_small_kernel<<<1, 64, 0, stream>>>(S, cm, (const float*)d_in[29], (const float*)d_in[30], cvec);
    head_out_kernel<<<256, 256, 0, stream>>>(ALLb, musig2, cvec,
                                             (const float*)d_in[31], (const float*)d_in[32],
                                             (const float*)d_in[33], (float*)d_out);
}

// Round 16
// 334.143 us; speedup vs baseline: 1.0463x; 1.0463x over previous
//
#include <hip/hip_runtime.h>
#include <hip/hip_fp16.h>
#include <math.h>

#define DIM 64
#define M_FINAL (128*89)   // 11392 final rows

static inline int cdiv(int a, int b) { return (a + b - 1) / b; }

typedef _Float16 v8h __attribute__((ext_vector_type(8)));
typedef _Float16 v4h __attribute__((ext_vector_type(4)));
typedef float v4f __attribute__((ext_vector_type(4)));

__device__ inline float rdlane(float v, int l) {
    return __int_as_float(__builtin_amdgcn_readlane(__float_as_int(v), l));
}
__device__ inline unsigned packpw(float p, unsigned src) {
    return ((unsigned)__half_as_ushort(__float2half(p)) << 16) | src;
}
__device__ inline float unpackpw(unsigned ep) {
    return __half2float(__ushort_as_half((unsigned short)(ep >> 16)));
}
__device__ inline __half2 u2h2(unsigned u) {
    union { unsigned u; __half2 h; } c; c.u = u; return c.h;
}

struct EdgeSets {
    const int* src[12];
    const int* dst[12];
    int ne[12];
};

struct L0Args {
    const float* x;
    __half* out[4];
    const int* rowptr[4];
    const int* colsrc[4];
    int ne[4];
    int nemax;
    double* dstats;
    const float* W;
    const float* as;
    const float* ad;
    const float* bias;
};

struct AggArgs {
    const __half* hp[4];      // projected rows (out-space, fp16)
    void* out[4];
    const int* rowptr[4];
    const int* colsrc[4];
    int ne[4];
    int nemax;
    const float* sS;          // [j][g][NPIN]
    const float* sD;
    const float* bias;
    double* dstats;
};

// ---------------- misc ----------------

__global__ void zero_kernel(float* __restrict__ p, int n) {
    int i = blockIdx.x * blockDim.x + threadIdx.x;
    if (i < n) p[i] = 0.f;
}

// ---------------- fused CSR build: one block per edge set ------------------
__global__ __launch_bounds__(768)
void csr_build_kernel(EdgeSets ES, int* __restrict__ rowptr_all,
                      int* __restrict__ colsrc_all) {
    __shared__ int cnt[768];
    __shared__ int cur[768];
    const int s = blockIdx.x;
    const int lay = s % 3;
    const int n = (lay == 0) ? 706 : (lay == 1) ? 353 : 177;
    const int ne = ES.ne[s];
    const int* __restrict__ src = ES.src[s];
    const int* __restrict__ dst = ES.dst[s];
    int* __restrict__ rowptr = rowptr_all + s * 768;
    int* __restrict__ colsrc = colsrc_all + s * 8192;
    const int t = threadIdx.x;

    cnt[t] = 0;
    __syncthreads();
    for (int k = t; k < ne; k += 768) atomicAdd(&cnt[dst[k]], 1);
    __syncthreads();
    int v = cnt[t];
    for (int off = 1; off < 768; off <<= 1) {
        int add = (t >= off) ? cnt[t - off] : 0;
        __syncthreads();
        cnt[t] += add;
        __syncthreads();
    }
    int excl = cnt[t] - v;
    if (t < n) { rowptr[t] = excl; cur[t] = excl; }
    if (t == n - 1) rowptr[n] = cnt[t];
    __syncthreads();
    for (int k = t; k < ne; k += 768) {
        int pos = atomicAdd(&cur[dst[k]], 1);
        colsrc[pos] = src[k];
    }
}

// ---------------- layer 0 mega kernel (in_dim=3, thread-par agg) -----------
// grid = split(2) x view(4) x graph(128) = 1024 blocks of 512 threads.
__global__ __launch_bounds__(512, 8)
void layer0_kernel(L0Args A) {
    constexpr int NPIN = 706, NPOUT = 353, HALF = 177;

    extern __shared__ char smem[];
    float* sredF = (float*)smem;                       // [2][8][64] = 4096 B
    float* fp = (float*)(smem + 4096);
    float* sSrc = fp; fp += NPIN;
    float* sDst = fp; fp += NPIN;
    float* hL4  = fp; fp += NPIN * 4;
    float* agg4 = fp; fp += 356 * 4;
    float* waL0 = fp; fp += 8;
    unsigned short* rp16 = (unsigned short*)fp;        // 708

    const int split = blockIdx.x >> 9;
    const int jg = blockIdx.x & 511;
    const int j = jg >> 7;
    const int g = jg & 127;
    const int tid = threadIdx.x;
    const int wave = tid >> 6;
    const int lane = tid & 63;

    const int n0c = split * HALF;
    const int n1c = min(NPOUT, n0c + HALF);
    const int ch0 = 2 * n0c;
    const int ch1 = 2 * n1c;          // NPIN even -> always valid children

    const int* __restrict__ rowptr = A.rowptr[j];
    const int* __restrict__ colsrc = A.colsrc[j];
    const float* __restrict__ W = A.W;

    for (int k = tid; k <= NPIN; k += 512) rp16[k] = (unsigned short)rowptr[k];
    if (tid < 6) {                    // wa_{src,dst}[f] = sum_d W[f][d]*a[d]
        int f = (tid < 3) ? tid : tid - 3;
        const float* av = (tid < 3) ? A.as : A.ad;
        float acc = 0.f;
        for (int d = 0; d < 64; ++d) acc += W[f * 64 + d] * av[d];
        waL0[tid] = acc;
    }
    __syncthreads();

    // h staging + s-dots
    {
        const float* hb = A.x + (size_t)g * (NPIN * 3);
        for (int r = tid; r < NPIN; r += 512) {
            float h0 = hb[r * 3], h1 = hb[r * 3 + 1], h2 = hb[r * 3 + 2];
            hL4[r * 4] = h0; hL4[r * 4 + 1] = h1; hL4[r * 4 + 2] = h2; hL4[r * 4 + 3] = 0.f;
            sSrc[r] = h0 * waL0[0] + h1 * waL0[1] + h2 * waL0[2];
            sDst[r] = h0 * waL0[3] + h1 * waL0[4] + h2 * waL0[5];
        }
    }
    __syncthreads();

    // thread-par softmax + aggregation: one child per thread
    const int child = ch0 + tid;
    if (child < ch1) {
        int s0 = rp16[child], e0 = rp16[child + 1];
        float sd = sDst[child];
        float m = -1e30f;
        for (int k = s0; k < e0; ++k) {
            float v = sSrc[colsrc[k]] + sd;
            v = (v >= 0.f) ? v : 0.2f * v;
            m = fmaxf(m, v);
        }
        float z = 0.f, a0 = 0.f, a1 = 0.f, a2 = 0.f;
        for (int k = s0; k < e0; ++k) {
            int sl = colsrc[k];
            float v = sSrc[sl] + sd;
            v = (v >= 0.f) ? v : 0.2f * v;
            float p = __expf(v - m);
            z += p;
            a0 += p * hL4[sl * 4];
            a1 += p * hL4[sl * 4 + 1];
            a2 += p * hL4[sl * 4 + 2];
        }
        float iz = 1.f / z;
        agg4[tid * 4]     = a0 * iz;
        agg4[tid * 4 + 1] = a1 * iz;
        agg4[tid * 4 + 2] = a2 * iz;
        agg4[tid * 4 + 3] = 0.f;
    }
    __syncthreads();

    // wave-par matvec + relu + pool + store + BN stats
    const float w0 = W[lane], w1 = W[64 + lane], w2 = W[128 + lane];
    const float b_l = A.bias[lane];
    __half* outj = A.out[j];
    const float4* agg4v = (const float4*)agg4;
    float bs = 0.f, bs2 = 0.f;

    for (int c = n0c + wave; c < n1c; c += 8) {
        int lc = 2 * (c - n0c);
        float4 va = agg4v[lc];
        float4 vb = agg4v[lc + 1];
        float oa = va.x * w0 + va.y * w1 + va.z * w2 + b_l;
        float ob = vb.x * w0 + vb.y * w1 + vb.z * w2 + b_l;
        float vmax = fmaxf(fmaxf(oa, ob), 0.f);
        outj[((size_t)g * NPOUT + c) * 64 + lane] = __float2half(vmax);
        bs += vmax;
        bs2 += vmax * vmax;
    }
    sredF[wave * 64 + lane] = bs;
    sredF[512 + wave * 64 + lane] = bs2;
    __syncthreads();
    if (wave == 0) {
        float t1 = 0.f, t2 = 0.f;
        #pragma unroll
        for (int w = 0; w < 8; ++w) {
            t1 += sredF[w * 64 + lane];
            t2 += sredF[512 + w * 64 + lane];
        }
        atomicAdd(A.dstats + j * 128 + lane, (double)t1);
        atomicAdd(A.dstats + j * 128 + 64 + lane, (double)t2);
    }
}

// BN finalize; optionally fold stats into next layer's weight:
// Wp[f][d] = rs[f]*Wn[f][d]; csh[d] = sum_f mu[f]*rs[f]*Wn[f][d]
__global__ void bn_finalize_kernel(const double* __restrict__ dstats,
                                   float* __restrict__ musig, int n_rows,
                                   const float* __restrict__ Wn,
                                   float* __restrict__ Wp, float* __restrict__ csh) {
    __shared__ float mur[128];
    int jv = blockIdx.x;           // view
    int d = threadIdx.x;           // 64
    double mu = dstats[jv * 128 + d] / n_rows;
    double var = dstats[jv * 128 + 64 + d] / n_rows - mu * mu;
    float rs = rsqrtf((float)var + 1e-5f);
    musig[jv * 128 + d] = (float)mu;
    musig[jv * 128 + 64 + d] = rs;
    if (Wn != nullptr) {
        mur[d] = (float)mu; mur[64 + d] = rs;
        __syncthreads();
        float c = 0.f;
        for (int f = 0; f < 64; ++f) {
            float wp = mur[64 + f] * Wn[f * 64 + d];
            Wp[jv * 4096 + f * 64 + d] = wp;
            c += mur[f] * wp;
        }
        csh[jv * 64 + d] = c;
    }
}

// ---------------- projection via MFMA: HP = h @ W' - c, fp16 in-place ------
__global__ __launch_bounds__(256, 4)
void proj_kernel(__half* __restrict__ buf, const float* __restrict__ Wp_all,
                 const float* __restrict__ csh_all,
                 const float* __restrict__ a_s, const float* __restrict__ a_d,
                 float* __restrict__ sS, float* __restrict__ sD, int npin) {
    __shared__ _Float16 Wt[64 * 64];   // Wt[d][f] = W'[f][d], fp16 (8 KB)
    const int j = blockIdx.y;
    const int tid = threadIdx.x;
    const int lane = tid & 63, wave = tid >> 6;
    const int lc = lane & 15, quad = lane >> 4;
    const int R = 128 * npin;          // multiple of 16
    __half* h = buf + (size_t)j * R * 64;
    const float* Wp = Wp_all + j * 4096;

    for (int k = tid; k < 4096; k += 256) {
        int f = k >> 6, d = k & 63;
        Wt[d * 64 + f] = (_Float16)Wp[k];
    }
    __syncthreads();

    v8h bfrag[4][2];
    #pragma unroll
    for (int t = 0; t < 4; ++t)
        #pragma unroll
        for (int s = 0; s < 2; ++s)
            bfrag[t][s] = *(const v8h*)&Wt[(t * 16 + lc) * 64 + s * 32 + quad * 8];

    float cshv[4], asv[4], adv[4];
    #pragma unroll
    for (int t = 0; t < 4; ++t) {
        cshv[t] = csh_all[j * 64 + t * 16 + lc];
        asv[t] = a_s[t * 16 + lc];
        adv[t] = a_d[t * 16 + lc];
    }

    const int ntiles = R >> 4;
    for (int tile = blockIdx.x * 4 + wave; tile < ntiles; tile += gridDim.x * 4) {
        const int rowbase = tile * 16;
        const __half* arow = h + ((size_t)(rowbase + lc)) * 64 + quad * 8;
        v8h a0 = *(const v8h*)arow;            // k-step 0 (k=0..31)
        v8h a1 = *(const v8h*)(arow + 32);     // k-step 1 (k=32..63)
        v4f acc[4];
        #pragma unroll
        for (int t = 0; t < 4; ++t) {
            acc[t] = (v4f){0.f, 0.f, 0.f, 0.f};
            acc[t] = __builtin_amdgcn_mfma_f32_16x16x32_f16(a0, bfrag[t][0], acc[t], 0, 0, 0);
            acc[t] = __builtin_amdgcn_mfma_f32_16x16x32_f16(a1, bfrag[t][1], acc[t], 0, 0, 0);
        }
        float pS[4] = {0.f, 0.f, 0.f, 0.f};
        float pD[4] = {0.f, 0.f, 0.f, 0.f};
        #pragma unroll
        for (int t = 0; t < 4; ++t) {
            #pragma unroll
            for (int r = 0; r < 4; ++r) {
                float o = acc[t][r] - cshv[t];
                h[((size_t)(rowbase + quad * 4 + r)) * 64 + t * 16 + lc] = __float2half(o);
                pS[r] += o * asv[t];
                pD[r] += o * adv[t];
            }
        }
        #pragma unroll
        for (int m = 1; m < 16; m <<= 1) {
            #pragma unroll
            for (int r = 0; r < 4; ++r) {
                pS[r] += __shfl_xor(pS[r], m, 64);
                pD[r] += __shfl_xor(pD[r], m, 64);
            }
        }
        if (lc == 0) {
            #pragma unroll
            for (int r = 0; r < 4; ++r) {
                sS[j * R + rowbase + quad * 4 + r] = pS[r];
                sD[j * R + rowbase + quad * 4 + r] = pD[r];
            }
        }
    }
}

// ---------------- aggregation (L>0): quad-row gather, packed fp16 FMA ------
// wave = (edge-group qg = lane>>4) x (dim-group lc = lane&15, 4 dims/lane).
// One 8B load per lane covers 4 edges' rows; v_pk_fma_f16 accumulates
// 2 MACs/inst with no converts; fp32 conversion once per child.
template<int NPIN, typename OutT>
__global__ __launch_bounds__(512, 8)
void agg_kernel(AggArgs A) {
    constexpr int NPOUT = (NPIN + 1) / 2;
    constexpr int HALF = (NPOUT + 1) / 2;

    extern __shared__ char smem[];
    float* sredF = (float*)smem;                       // 4096 B
    float* fp = (float*)(smem + 4096);
    float* sSrc = fp; fp += NPIN;
    float* sDst = fp; fp += NPIN;
    unsigned* ep32 = (unsigned*)fp;
    unsigned short* rp16 = (unsigned short*)(ep32 + A.nemax);

    const int split = blockIdx.x >> 9;
    const int jg = blockIdx.x & 511;
    const int j = jg >> 7;
    const int g = jg & 127;
    const int tid = threadIdx.x;
    const int wave = tid >> 6;
    const int lane = tid & 63;
    const int qg = lane >> 4;          // edge-group 0..3
    const int lc = lane & 15;          // dim-group: dims 4*lc .. 4*lc+3

    const int n0c = split * HALF;
    const int n1c = min(NPOUT, n0c + HALF);
    const int ch0 = 2 * n0c;
    const int ch1 = min(NPIN, 2 * n1c);

    const int* __restrict__ rowptr = A.rowptr[j];
    const int* __restrict__ colsrc = A.colsrc[j];
    const int ne = A.ne[j];
    const int sbase = (j * 128 + g) * NPIN;
    const __half* __restrict__ hpb = A.hp[j] + (size_t)g * NPIN * 64 + 4 * lc;

    for (int k = tid; k <= NPIN; k += 512) rp16[k] = (unsigned short)rowptr[k];
    for (int k = tid; k < ne; k += 512) ep32[k] = (unsigned)colsrc[k];
    for (int r = tid; r < NPIN; r += 512) {
        sSrc[r] = A.sS[sbase + r];
        sDst[r] = A.sD[sbase + r];
    }
    __syncthreads();

    // per-node online softmax -> packed fp16 weights (own child range)
    for (int r = ch0 + tid; r < ch1; r += 512) {
        int s0 = rp16[r], e0 = rp16[r + 1];
        float sd = sDst[r];
        float m = -1e30f, z = 0.f;
        for (int k = s0; k < e0; ++k) {
            float v = sSrc[ep32[k] & 0xFFFFu] + sd;
            v = (v >= 0.f) ? v : 0.2f * v;
            if (v > m) { z = z * __expf(m - v) + 1.f; m = v; }
            else z += __expf(v - m);
        }
        float invz = 1.f / z;
        for (int k = s0; k < e0; ++k) {
            unsigned sl = ep32[k] & 0xFFFFu;
            float v = sSrc[sl] + sd;
            v = (v >= 0.f) ? v : 0.2f * v;
            ep32[k] = packpw(__expf(v - m) * invz, sl);
        }
    }
    __syncthreads();

    const float4 b4 = *(const float4*)(A.bias + 4 * lc);
    OutT* outj = (OutT*)A.out[j];
    float bs[4] = {0.f, 0.f, 0.f, 0.f};
    float bs2[4] = {0.f, 0.f, 0.f, 0.f};

    for (int c = n0c + wave; c < n1c; c += 8) {
        float vch[2][4];
        #pragma unroll
        for (int ch = 0; ch < 2; ++ch) {
            __half2 aA0 = u2h2(0), aA1 = u2h2(0);   // accum chain A (dims 01,23)
            __half2 aB0 = u2h2(0), aB1 = u2h2(0);   // accum chain B
            int child = 2 * c + ch;
            if (child < NPIN) {
                int s0 = rp16[child], e0 = rp16[child + 1];
                int k = s0;
                for (; k + 8 <= e0; k += 8) {
                    unsigned e0p = ep32[k + qg];
                    unsigned e1p = ep32[k + 4 + qg];
                    uint2 u0 = *(const uint2*)(hpb + (size_t)(e0p & 0xFFFFu) * 64);
                    uint2 u1 = *(const uint2*)(hpb + (size_t)(e1p & 0xFFFFu) * 64);
                    __half2 p0 = u2h2((e0p & 0xFFFF0000u) | (e0p >> 16));
                    __half2 p1 = u2h2((e1p & 0xFFFF0000u) | (e1p >> 16));
                    aA0 = __hfma2(u2h2(u0.x), p0, aA0);
                    aA1 = __hfma2(u2h2(u0.y), p0, aA1);
                    aB0 = __hfma2(u2h2(u1.x), p1, aB0);
                    aB1 = __hfma2(u2h2(u1.y), p1, aB1);
                }
                for (; k < e0; k += 4) {
                    int idx = k + qg;
                    unsigned ep = ep32[(idx < e0) ? idx : (e0 - 1)];
                    uint2 u0 = *(const uint2*)(hpb + (size_t)(ep & 0xFFFFu) * 64);
                    unsigned pb = (idx < e0) ? ((ep & 0xFFFF0000u) | (ep >> 16)) : 0u;
                    __half2 p0 = u2h2(pb);
                    aA0 = __hfma2(u2h2(u0.x), p0, aA0);
                    aA1 = __hfma2(u2h2(u0.y), p0, aA1);
                }
            }
            float2 f0 = __half22float2(aA0), f1 = __half22float2(aA1);
            float2 g0 = __half22float2(aB0), g1 = __half22float2(aB1);
            vch[ch][0] = f0.x + g0.x;
            vch[ch][1] = f0.y + g0.y;
            vch[ch][2] = f1.x + g1.x;
            vch[ch][3] = f1.y + g1.y;
        }
        // reduce over the 4 edge-groups
        #pragma unroll
        for (int m = 16; m < 64; m <<= 1) {
            #pragma unroll
            for (int r = 0; r < 4; ++r) {
                vch[0][r] += __shfl_xor(vch[0][r], m, 64);
                vch[1][r] += __shfl_xor(vch[1][r], m, 64);
            }
        }
        float vm[4];
        #pragma unroll
        for (int r = 0; r < 4; ++r) {
            float oa = vch[0][r] + ((const float*)&b4)[r];
            float ob = vch[1][r] + ((const float*)&b4)[r];
            vm[r] = fmaxf(fmaxf(oa, ob), 0.f);
            bs[r] += vm[r];
            bs2[r] += vm[r] * vm[r];
        }
        if (qg == 0) {
            if constexpr (sizeof(OutT) == 2) {
                v4h hv;
                #pragma unroll
                for (int r = 0; r < 4; ++r) hv[r] = (_Float16)vm[r];
                *(v4h*)((__half*)outj + ((size_t)g * NPOUT + c) * 64 + 4 * lc) = hv;
            } else {
                float4 fv = {vm[0], vm[1], vm[2], vm[3]};
                *(float4*)((float*)outj + ((size_t)g * NPOUT + c) * 64 + 4 * lc) = fv;
            }
        }
    }
    // stats: post-reduce values identical across qg; qg==0 lanes cover all 64 dims
    if (qg == 0) {
        #pragma unroll
        for (int r = 0; r < 4; ++r) {
            sredF[wave * 64 + 4 * lc + r] = bs[r];
            sredF[512 + wave * 64 + 4 * lc + r] = bs2[r];
        }
    }
    __syncthreads();
    if (wave == 0) {
        float t1 = 0.f, t2 = 0.f;
        #pragma unroll
        for (int w = 0; w < 8; ++w) {
            t1 += sredF[w * 64 + lane];
            t2 += sredF[512 + w * 64 + lane];
        }
        atomicAdd(A.dstats + j * 128 + lane, (double)t1);
        atomicAdd(A.dstats + j * 128 + 64 + lane, (double)t2);
    }
}

// ---------------- fused head reduce: Bm dots -> S (BmT Bm) + column means --
__global__ __launch_bounds__(256)
void head_reduce_kernel(const float* __restrict__ ALL, const float* __restrict__ musig,
                        const float* __restrict__ w_attn,
                        float* __restrict__ S, float* __restrict__ cm) {
    __shared__ float S_loc[16];
    __shared__ float cm_loc[256];
    const int t = threadIdx.x, wave = t >> 6, lane = t & 63;
    if (t < 16) S_loc[t] = 0.f;
    cm_loc[t] = 0.f;
    __syncthreads();
    const float wa = w_attn[lane];
    float cacc[4] = {0.f, 0.f, 0.f, 0.f};
    for (int m = blockIdx.x * 4 + wave; m < M_FINAL; m += gridDim.x * 4) {
        float b4[4];
        float csum = 0.f;
        #pragma unroll
        for (int v = 0; v < 4; ++v) {
            float val = (ALL[((size_t)v * M_FINAL + m) * 64 + lane] - musig[v * 128 + lane])
                        * musig[v * 128 + 64 + lane];
            csum += val;
            float p = val * wa;
            for (int off = 32; off > 0; off >>= 1) p += __shfl_down(p, off, 64);
            b4[v] = __shfl(p, 0, 64);
        }
        cacc[m & 3] += csum;
        if (lane < 16) atomicAdd(&S_loc[lane], b4[lane >> 2] * b4[lane & 3]);
    }
    #pragma unroll
    for (int q = 0; q < 4; ++q) atomicAdd(&cm_loc[q * 64 + lane], cacc[q]);
    __syncthreads();
    if (t < 16) atomicAdd(&S[t], S_loc[t]);
    atomicAdd(&cm[t], cm_loc[t]);
}

// wave-parallel: 64 lanes split the 256-column mean-dot; lane 0 does the
// tiny 4x4 softmax tail.
__global__ void fuse_small_kernel(const float* __restrict__ S, const float* __restrict__ cm,
                                  const float* __restrict__ w_lin0, const float* __restrict__ b_lin0,
                                  float* __restrict__ cvec) {
    const int lane = threadIdx.x;      // 64
    float pa0 = 0.f, pa1 = 0.f, pa2 = 0.f, pa3 = 0.f;
    #pragma unroll
    for (int q = 0; q < 4; ++q) {
        int c = q * 64 + lane;
        float cmv = cm[c] / (float)M_FINAL;
        pa0 += cmv * w_lin0[c * 4 + 0];
        pa1 += cmv * w_lin0[c * 4 + 1];
        pa2 += cmv * w_lin0[c * 4 + 2];
        pa3 += cmv * w_lin0[c * 4 + 3];
    }
    for (int off = 32; off > 0; off >>= 1) {
        pa0 += __shfl_down(pa0, off, 64);
        pa1 += __shfl_down(pa1, off, 64);
        pa2 += __shfl_down(pa2, off, 64);
        pa3 += __shfl_down(pa3, off, 64);
    }
    if (lane != 0) return;
    float e4[4] = {pa0 + b_lin0[0], pa1 + b_lin0[1], pa2 + b_lin0[2], pa3 + b_lin0[3]};
    float cn[4];
    for (int v = 0; v < 4; ++v) cn[v] = sqrtf(S[v * 4 + v]);
    float A[16];
    for (int u = 0; u < 4; ++u) {
        float row[4]; float mx = -1e30f;
        for (int v = 0; v < 4; ++v) {
            float g = S[u * 4 + v] / (cn[u] * cn[v]);
            g = (g >= 0.f) ? g : 0.1f * g;       // leaky_relu 0.1
            row[v] = g; mx = fmaxf(mx, g);
        }
        float sum = 0.f;
        for (int v = 0; v < 4; ++v) { row[v] = expf(row[v] - mx); sum += row[v]; }
        for (int v = 0; v < 4; ++v) A[u * 4 + v] = row[v] / sum;
    }
    float mx = fmaxf(fmaxf(e4[0], e4[1]), fmaxf(e4[2], e4[3]));
    float sum = 0.f, w[4];
    for (int v = 0; v < 4; ++v) { w[v] = expf(e4[v] - mx); sum += w[v]; }
    for (int v = 0; v < 4; ++v) w[v] /= sum;
    for (int k = 0; k < 4; ++k) {
        float c = 0.f;
        for (int v = 0; v < 4; ++v) c += A[k * 4 + v] * w[v];
        cvec[k] = c;
    }
}

// ---------------- fused head output: combine + 3 matvecs (selu,selu,none) --
__global__ __launch_bounds__(256)
void head_out_kernel(const float* __restrict__ ALL, const float* __restrict__ musig,
                     const float* __restrict__ cvec,
                     const float* __restrict__ W0, const float* __restrict__ W1,
                     const float* __restrict__ W2, float* __restrict__ outp) {
    __shared__ float Wl[3][64 * 64];   // 48 KB
    const int t = threadIdx.x, wave = t >> 6, lane = t & 63;
    for (int k = t; k < 4096; k += 256) {
        Wl[0][k] = W0[k]; Wl[1][k] = W1[k]; Wl[2][k] = W2[k];
    }
    __syncthreads();
    const float c0 = cvec[0], c1 = cvec[1], c2 = cvec[2], c3 = cvec[3];
    const float scale = 1.0507009873554805f;
    const float alpha = 1.6732632423543772f;
    for (int m = blockIdx.x * 4 + wave; m < M_FINAL; m += gridDim.x * 4) {
        float r =
            c0 * ((ALL[((size_t)0 * M_FINAL + m) * 64 + lane] - musig[0 * 128 + lane]) * musig[0 * 128 + 64 + lane]) +
            c1 * ((ALL[((size_t)1 * M_FINAL + m) * 64 + lane] - musig[1 * 128 + lane]) * musig[1 * 128 + 64 + lane]) +
            c2 * ((ALL[((size_t)2 * M_FINAL + m) * 64 + lane] - musig[2 * 128 + lane]) * musig[2 * 128 + 64 + lane]) +
            c3 * ((ALL[((size_t)3 * M_FINAL + m) * 64 + lane] - musig[3 * 128 + lane]) * musig[3 * 128 + 64 + lane]);
        #pragma unroll
        for (int s = 0; s < 3; ++s) {
            float o0 = 0.f, o1 = 0.f, o2 = 0.f, o3 = 0.f;
            #pragma unroll
            for (int f = 0; f < 64; f += 4) {
                o0 += rdlane(r, f)     * Wl[s][f * 64 + lane];
                o1 += rdlane(r, f + 1) * Wl[s][(f + 1) * 64 + lane];
                o2 += rdlane(r, f + 2) * Wl[s][(f + 2) * 64 + lane];
                o3 += rdlane(r, f + 3) * Wl[s][(f + 3) * 64 + lane];
            }
            float o = (o0 + o1) + (o2 + o3);
            if (s < 2) o = (o > 0.f) ? scale * o : scale * alpha * expm1f(o);
            r = o;
        }
        outp[(size_t)m * 64 + lane] = r;
    }
}

extern "C" void kernel_launch(void* const* d_in, const int* in_sizes, int n_in,
                              void* d_out, int out_size, void* d_ws, size_t ws_size,
                              hipStream_t stream) {
    const float* x = (const float*)d_in[15];

    float* ws = (float*)d_ws;
    double* dstats_all = (double*)ws;                 // 1536 doubles -> [0, 3072)
    float*  cm         = ws + 3072;                   // 256
    float*  S          = ws + 3328;                   // 16
    float*  cvec       = ws + 3344;                   // 4
    float*  musig_all  = ws + 3584;                   // 3*512 -> [3584, 5120)
    float*  Wp_all     = ws + 5120;                   // 2*4*4096 -> [5120, 37888)
    float*  csh_all    = ws + 37888;                  // 2*4*64 -> [37888, 38400)
    int*    rowptr_all = (int*)(ws + 38400);          // 12*768 -> [38400, 47616)
    int*    colsrc_all = (int*)(ws + 47616);          // 12*8192 -> [47616, 145920)
    float*  sS1        = ws + 145920;                 // 180736
    float*  sD1        = sS1 + 180736;
    float*  sS2        = sD1 + 180736;                // 90624
    float*  sD2        = sS2 + 90624;
    __half* A16        = (__half*)(sD2 + 90624);      // 11,567,104 halves (5,783,552 slots)
    __half* B16        = (__half*)((float*)A16 + 5783552);  // 5,799,936 halves (2,899,968 slots)
    float*  ALLb       = (float*)B16 + 2899968;       // 2,916,352 floats
    const size_t as0h = (size_t)128 * 353 * 64;       // halves per view (layer0/1)
    const size_t as1h = (size_t)128 * 177 * 64;

    // edge sets (graph-0 structure shared by all 128 graphs)
    EdgeSets ES;
    int nemax[3] = {0, 0, 0};
    for (int s = 0; s < 12; ++s) {
        const int* e = (const int*)d_in[s];
        int E = in_sizes[s] / 2;
        ES.src[s] = e;
        ES.dst[s] = e + E;
        ES.ne[s] = E / 128;
        int lay = s % 3;
        if (ES.ne[s] > nemax[lay]) nemax[lay] = ES.ne[s];
    }

    // dynamic LDS sizes (mirror in-kernel layouts)
    int SM0 = 4096 + (706 * 6 + 356 * 4 + 8) * 4 + 708 * 2;
    SM0 = (SM0 + 15) & ~15;
    int SMa1 = 4096 + (2 * 353) * 4 + nemax[1] * 4 + 355 * 2;
    SMa1 = (SMa1 + 15) & ~15;
    int SMa2 = 4096 + (2 * 177) * 4 + nemax[2] * 4 + 179 * 2;
    SMa2 = (SMa2 + 15) & ~15;
    (void)hipFuncSetAttribute(reinterpret_cast<const void*>(&layer0_kernel),
                              hipFuncAttributeMaxDynamicSharedMemorySize, SM0);
    (void)hipFuncSetAttribute(reinterpret_cast<const void*>(&agg_kernel<353, __half>),
                              hipFuncAttributeMaxDynamicSharedMemorySize, SMa1);
    (void)hipFuncSetAttribute(reinterpret_cast<const void*>(&agg_kernel<177, float>),
                              hipFuncAttributeMaxDynamicSharedMemorySize, SMa2);

    zero_kernel<<<cdiv(3584, 256), 256, 0, stream>>>(ws, 3584);
    csr_build_kernel<<<12, 768, 0, stream>>>(ES, rowptr_all, colsrc_all);

    // ---- layer 0 -> fp16 raw0 in A16 ----
    {
        L0Args A;
        A.x = x;
        for (int j = 0; j < 4; ++j) {
            int s = j * 3;
            A.rowptr[j] = rowptr_all + s * 768;
            A.colsrc[j] = colsrc_all + s * 8192;
            A.ne[j] = ES.ne[s];
            A.out[j] = A16 + j * as0h;
        }
        A.nemax = nemax[0];
        A.dstats = dstats_all;
        A.W = (const float*)d_in[16];
        A.as = (const float*)d_in[17];
        A.ad = (const float*)d_in[18];
        A.bias = (const float*)d_in[19];
        layer0_kernel<<<1024, 512, SM0, stream>>>(A);
    }
    bn_finalize_kernel<<<4, 64, 0, stream>>>(dstats_all, musig_all, 128 * 353,
                                             (const float*)d_in[20], Wp_all, csh_all);

    // ---- layer 1: in-place fp16 MFMA proj on A16, then aggregate -> B16 ---
    proj_kernel<<<dim3(256, 4), 256, 0, stream>>>(A16, Wp_all, csh_all,
                                                  (const float*)d_in[21], (const float*)d_in[22],
                                                  sS1, sD1, 353);
    {
        AggArgs A;
        for (int j = 0; j < 4; ++j) {
            int s = j * 3 + 1;
            A.rowptr[j] = rowptr_all + s * 768;
            A.colsrc[j] = colsrc_all + s * 8192;
            A.ne[j] = ES.ne[s];
            A.hp[j] = A16 + j * as0h;
            A.out[j] = B16 + j * as1h;
        }
        A.nemax = nemax[1];
        A.sS = sS1; A.sD = sD1;
        A.bias = (const float*)d_in[23];
        A.dstats = dstats_all + 512;
        agg_kernel<353, __half><<<1024, 512, SMa1, stream>>>(A);
    }
    bn_finalize_kernel<<<4, 64, 0, stream>>>(dstats_all + 512, musig_all + 512, 128 * 177,
                                             (const float*)d_in[24], Wp_all + 16384, csh_all + 256);

    // ---- layer 2: in-place fp16 MFMA proj on B16, then aggregate -> ALLb --
    proj_kernel<<<dim3(256, 4), 256, 0, stream>>>(B16, Wp_all + 16384, csh_all + 256,
                                                  (const float*)d_in[25], (const float*)d_in[26],
                                                  sS2, sD2, 177);
    {
        AggArgs A;
        for (int j = 0; j < 4; ++j) {
            int s = j * 3 + 2;
            A.rowptr[j] = rowptr_all + s * 768;
            A.colsrc[j] = colsrc_all + s * 8192;
            A.ne[j] = ES.ne[s];
            A.hp[j] = B16 + j * as1h;
            A.out[j] = ALLb + (size_t)j * M_FINAL * 64;
        }
        A.nemax = nemax[2];
        A.sS = sS2; A.sD = sD2;
        A.bias = (const float*)d_in[27];
        A.dstats = dstats_all + 1024;
        agg_kernel<177, float><<<1024, 512, SMa2, stream>>>(A);
    }
    bn_finalize_kernel<<<4, 64, 0, stream>>>(dstats_all + 1024, musig_all + 1024, 128 * 89,
                                             nullptr, nullptr, nullptr);

    // ---- fusion head ----
    const float* musig2 = musig_all + 1024;
    head_reduce_kernel<<<256, 256, 0, stream>>>(ALLb, musig2, (const float*)d_in[28], S, cm);
    fuse_small_kernel<<<1, 64, 0, stream>>>(S, cm, (const float*)d_in[29], (const float*)d_in[30], cvec);
    head_out_kernel<<<256, 256, 0, stream>>>(ALLb, musig2, cvec,
                                             (const float*)d_in[31], (const float*)d_in[32],
                                             (const float*)d_in[33], (float*)d_out);
}